// Round 1
// baseline (2008.555 us; speedup 1.0000x reference)
//
#include <hip/hip_runtime.h>
#include <math.h>

// ResDCN: discrete embed -> linear -> 2x GCNConv -> ResDNN(2) -> CrossNet(2) -> MLP -> sigmoid
// Sizes fixed by the problem:
constexpr int NCOLS   = 70;   // discrete feature columns
constexpr int NH      = 64;   // used columns
constexpr int EMB     = 128;  // graph embedding dim
constexpr int DD      = 192;  // NH + EMB
constexpr int RES_HID = 512;
constexpr int PRED_HID= 320;

__device__ __forceinline__ float leaky(float x){ return x > 0.f ? x : 0.01f*x; }

// ---- degree / normalization ---------------------------------------------
__global__ void k_deg_init(float* deg, int n){
  int i = blockIdx.x*256 + threadIdx.x;
  if (i < n) deg[i] = 1.0f;                 // +1 self loop
}
__global__ void k_deg_acc(const int* __restrict__ col, float* deg, int E){
  int e = blockIdx.x*256 + threadIdx.x;
  if (e < E) atomicAdd(&deg[col[e]], 1.0f);
}
__global__ void k_deg_fin(float* deg, int n){
  int i = blockIdx.x*256 + threadIdx.x;
  if (i < n) deg[i] = rsqrtf(deg[i]);       // deg buffer becomes dinv
}

// ---- discrete embedding: first 64 int cols -> float, into x[:,0:64] -----
__global__ void k_embed(const int* __restrict__ dx, float* __restrict__ A, int n){
  int idx = blockIdx.x*256 + threadIdx.x;
  if (idx < n*NH){
    int i = idx >> 6, j = idx & 63;
    A[i*DD + j] = (float)dx[i*NCOLS + j];
  }
}

// ---- generic row-tile GEMM: out[i, outoff+j] = act(bias[j] + X[i,:K] @ W[:,j]) ----
// 8 nodes per block, 256 threads. W is [K, J] row-major.
template<int K>
__global__ void k_gemm8(const float* __restrict__ X, int ldx,
                        const float* __restrict__ W, const float* __restrict__ bias,
                        int J, float* __restrict__ out, int ldo, int outoff,
                        int n, int act)
{
  __shared__ float sx[8][K];
  int i0 = blockIdx.x*8;
  for (int idx = threadIdx.x; idx < 8*K; idx += 256){
    int t = idx / K, k = idx - t*K;
    int i = i0 + t;
    sx[t][k] = (i < n) ? X[(size_t)i*ldx + k] : 0.f;
  }
  __syncthreads();
  for (int j = threadIdx.x; j < J; j += 256){
    float b = bias ? bias[j] : 0.f;
    float acc[8];
    #pragma unroll
    for (int t=0;t<8;t++) acc[t] = b;
    for (int k=0;k<K;k++){
      float w = W[(size_t)k*J + j];
      #pragma unroll
      for (int t=0;t<8;t++) acc[t] = fmaf(sx[t][k], w, acc[t]);
    }
    #pragma unroll
    for (int t=0;t<8;t++){
      int i = i0+t;
      if (i < n){
        float v = acc[t];
        if (act) v = leaky(v);
        out[(size_t)i*ldo + outoff + j] = v;
      }
    }
  }
}

// ---- GCN aggregation -----------------------------------------------------
// agg init: self-loop term h[i]*dinv[i]^2
__global__ void k_agg_init(const float* __restrict__ h, const float* __restrict__ dinv,
                           float* __restrict__ agg, int n){
  int idx = blockIdx.x*256 + threadIdx.x;
  if (idx < n*EMB){
    int i = idx >> 7;
    float di = dinv[i];
    agg[idx] = h[idx]*di*di;
  }
}
// scatter: agg[col] += h[row] * dinv[row]*dinv[col]; 2 edges per 256-thread block
__global__ void k_scatter(const int* __restrict__ row, const int* __restrict__ col,
                          const float* __restrict__ h, const float* __restrict__ dinv,
                          float* __restrict__ agg, int E){
  int e = blockIdx.x*2 + (threadIdx.x >> 7);
  int d = threadIdx.x & 127;
  if (e < E){
    int r = row[e], c = col[e];
    float nrm = dinv[r]*dinv[c];
    atomicAdd(&agg[(size_t)c*EMB + d], h[(size_t)r*EMB + d]*nrm);
  }
}
__global__ void k_bias_act(const float* __restrict__ agg, const float* __restrict__ bias,
                           float* __restrict__ out, int ldo, int outoff, int n){
  int idx = blockIdx.x*256 + threadIdx.x;
  if (idx < n*EMB){
    int i = idx >> 7, d = idx & 127;
    out[(size_t)i*ldo + outoff + d] = leaky(agg[idx] + bias[d]);
  }
}

// ---- fused residual bottleneck block: out = leaky(x + leaky(x@W1+b1)@W2 + b2) ----
__global__ void k_resblock(const float* __restrict__ X,
                           const float* __restrict__ W1, const float* __restrict__ b1,
                           const float* __restrict__ W2, const float* __restrict__ b2,
                           float* __restrict__ out, int n)
{
  __shared__ float sx[8][DD];
  __shared__ float sh[8][RES_HID];
  int i0 = blockIdx.x*8;
  for (int idx = threadIdx.x; idx < 8*DD; idx += 256){
    int t = idx / DD, k = idx - t*DD;
    int i = i0 + t;
    sx[t][k] = (i < n) ? X[(size_t)i*DD + k] : 0.f;
  }
  __syncthreads();
  for (int j = threadIdx.x; j < RES_HID; j += 256){
    float b = b1[j];
    float acc[8];
    #pragma unroll
    for (int t=0;t<8;t++) acc[t] = b;
    for (int k=0;k<DD;k++){
      float w = W1[(size_t)k*RES_HID + j];
      #pragma unroll
      for (int t=0;t<8;t++) acc[t] = fmaf(sx[t][k], w, acc[t]);
    }
    #pragma unroll
    for (int t=0;t<8;t++) sh[t][j] = leaky(acc[t]);
  }
  __syncthreads();
  for (int j = threadIdx.x; j < DD; j += 256){
    float b = b2[j];
    float acc[8];
    #pragma unroll
    for (int t=0;t<8;t++) acc[t] = b;
    for (int k=0;k<RES_HID;k++){
      float w = W2[(size_t)k*DD + j];
      #pragma unroll
      for (int t=0;t<8;t++) acc[t] = fmaf(sh[t][k], w, acc[t]);
    }
    #pragma unroll
    for (int t=0;t<8;t++){
      int i = i0+t;
      if (i < n) out[(size_t)i*DD + j] = leaky(sx[t][j] + acc[t]);
    }
  }
}

// ---- CrossNet: 2 layers, one wave per node -------------------------------
__global__ void k_cross(const float* __restrict__ X0, const float* __restrict__ cw,
                        const float* __restrict__ cb, float* __restrict__ out, int n)
{
  int node = blockIdx.x*4 + (threadIdx.x >> 6);
  int lane = threadIdx.x & 63;
  if (node >= n) return;
  const float* xr = X0 + (size_t)node*DD;
  float v0[3], xc[3];
  #pragma unroll
  for (int m=0;m<3;m++){ v0[m] = xr[lane + 64*m]; xc[m] = v0[m]; }
  #pragma unroll
  for (int l=0;l<2;l++){
    float p = 0.f;
    #pragma unroll
    for (int m=0;m<3;m++) p += xc[m]*cw[l*DD + lane + 64*m];
    #pragma unroll
    for (int off=32; off>0; off>>=1) p += __shfl_xor(p, off, 64);
    #pragma unroll
    for (int m=0;m<3;m++) xc[m] = v0[m]*p + cb[l*DD + lane + 64*m] + xc[m];
  }
  #pragma unroll
  for (int m=0;m<3;m++) out[(size_t)node*DD + lane + 64*m] = xc[m];
}

// ---- fused prediction head: y = sigmoid(leaky([deep,cross]@W1+b1) @ w2 + b2) ----
__global__ void k_pred(const float* __restrict__ deep, const float* __restrict__ cross,
                       const float* __restrict__ W1, const float* __restrict__ b1,
                       const float* __restrict__ w2, const float* __restrict__ b2,
                       float* __restrict__ y, int n)
{
  __shared__ float sz[8][2*DD];
  __shared__ float sred[4][8];
  int i0 = blockIdx.x*8;
  for (int idx = threadIdx.x; idx < 8*2*DD; idx += 256){
    int t = idx / (2*DD), k = idx - t*(2*DD);
    int i = i0 + t;
    float v = 0.f;
    if (i < n) v = (k < DD) ? deep[(size_t)i*DD + k] : cross[(size_t)i*DD + (k - DD)];
    sz[t][k] = v;
  }
  __syncthreads();
  float part[8];
  #pragma unroll
  for (int t=0;t<8;t++) part[t] = 0.f;
  for (int j = threadIdx.x; j < PRED_HID; j += 256){
    float b = b1[j];
    float w2j = w2[j];
    float acc[8];
    #pragma unroll
    for (int t=0;t<8;t++) acc[t] = b;
    for (int k=0;k<2*DD;k++){
      float w = W1[(size_t)k*PRED_HID + j];
      #pragma unroll
      for (int t=0;t<8;t++) acc[t] = fmaf(sz[t][k], w, acc[t]);
    }
    #pragma unroll
    for (int t=0;t<8;t++) part[t] += leaky(acc[t])*w2j;
  }
  #pragma unroll
  for (int t=0;t<8;t++){
    #pragma unroll
    for (int off=32; off>0; off>>=1) part[t] += __shfl_xor(part[t], off, 64);
  }
  int wave = threadIdx.x >> 6, lane = threadIdx.x & 63;
  if (lane == 0){
    #pragma unroll
    for (int t=0;t<8;t++) sred[wave][t] = part[t];
  }
  __syncthreads();
  if (threadIdx.x < 8){
    int t = threadIdx.x;
    float s = sred[0][t] + sred[1][t] + sred[2][t] + sred[3][t] + b2[0];
    int i = i0 + t;
    if (i < n) y[i] = 1.f/(1.f + expf(-s));
  }
}

extern "C" void kernel_launch(void* const* d_in, const int* in_sizes, int n_in,
                              void* d_out, int out_size, void* d_ws, size_t ws_size,
                              hipStream_t stream)
{
  const int*   dx      = (const int*)d_in[0];
  const int*   ei      = (const int*)d_in[1];
  const float* w_g0    = (const float*)d_in[2];
  const float* b_g0    = (const float*)d_in[3];
  const float* w_gcn1  = (const float*)d_in[4];
  const float* b_gcn1  = (const float*)d_in[5];
  const float* w_gcn2  = (const float*)d_in[6];
  const float* b_gcn2  = (const float*)d_in[7];
  const float* res_w1  = (const float*)d_in[8];
  const float* res_b1  = (const float*)d_in[9];
  const float* res_w2  = (const float*)d_in[10];
  const float* res_b2  = (const float*)d_in[11];
  const float* cross_w = (const float*)d_in[12];
  const float* cross_b = (const float*)d_in[13];
  const float* p_w1    = (const float*)d_in[14];
  const float* p_b1    = (const float*)d_in[15];
  const float* p_w2    = (const float*)d_in[16];
  const float* p_b2    = (const float*)d_in[17];
  float* y = (float*)d_out;

  int n = in_sizes[0] / NCOLS;
  int E = in_sizes[1] / 2;
  const int* row = ei;
  const int* col = ei + E;

  float* ws  = (float*)d_ws;
  float* A   = ws;                       // [n,192]  x (x0), cols 0..63 = x_d, 64..191 = x_g
  float* B   = A   + (size_t)n*DD;       // [n,192]  agg scratch, then x_deep
  float* Dx  = B   + (size_t)n*DD;       // [n,192]  x_cross
  float* E1  = Dx  + (size_t)n*DD;       // [n,128]  graph ping
  float* E2v = E1  + (size_t)n*EMB;      // [n,128]  graph pong
  float* deg = E2v + (size_t)n*EMB;      // [n]      deg -> dinv

  dim3 blk(256);
  int tiles = (n + 7)/8;

  // normalization
  k_deg_init<<<(n+255)/256, blk, 0, stream>>>(deg, n);
  k_deg_acc <<<(E+255)/256, blk, 0, stream>>>(col, deg, E);
  k_deg_fin <<<(n+255)/256, blk, 0, stream>>>(deg, n);
  // x_d
  k_embed<<<(n*NH+255)/256, blk, 0, stream>>>(dx, A, n);
  // x_g = leaky(x_d @ w_g0 + b_g0)
  k_gemm8<64><<<tiles, blk, 0, stream>>>(A, DD, w_g0, b_g0, EMB, E1, EMB, 0, n, 1);
  // GCN conv 1: E1 -> E1
  k_gemm8<128><<<tiles, blk, 0, stream>>>(E1, EMB, w_gcn1, nullptr, EMB, E2v, EMB, 0, n, 0);
  k_agg_init<<<(n*EMB+255)/256, blk, 0, stream>>>(E2v, deg, B, n);
  k_scatter <<<(E+1)/2, blk, 0, stream>>>(row, col, E2v, deg, B, E);
  k_bias_act<<<(n*EMB+255)/256, blk, 0, stream>>>(B, b_gcn1, E1, EMB, 0, n);
  // GCN conv 2: E1 -> A[:,64:192]
  k_gemm8<128><<<tiles, blk, 0, stream>>>(E1, EMB, w_gcn2, nullptr, EMB, E2v, EMB, 0, n, 0);
  k_agg_init<<<(n*EMB+255)/256, blk, 0, stream>>>(E2v, deg, B, n);
  k_scatter <<<(E+1)/2, blk, 0, stream>>>(row, col, E2v, deg, B, E);
  k_bias_act<<<(n*EMB+255)/256, blk, 0, stream>>>(B, b_gcn2, A, DD, NH, n);
  // ResDNN: A -> B, then B -> B (in-place safe: rows fully read into LDS first)
  k_resblock<<<tiles, blk, 0, stream>>>(A, res_w1, res_b1, res_w2, res_b2, B, n);
  k_resblock<<<tiles, blk, 0, stream>>>(B, res_w1 + (size_t)DD*RES_HID, res_b1 + RES_HID,
                                        res_w2 + (size_t)RES_HID*DD, res_b2 + DD, B, n);
  // CrossNet: A (x0) -> Dx
  k_cross<<<(n+3)/4, blk, 0, stream>>>(A, cross_w, cross_b, Dx, n);
  // prediction head
  k_pred<<<tiles, blk, 0, stream>>>(B, Dx, p_w1, p_b1, p_w2, p_b2, y, n);
}

// Round 2
// 1249.735 us; speedup vs baseline: 1.6072x; 1.6072x over previous
//
#include <hip/hip_runtime.h>
#include <math.h>

constexpr int NCOLS   = 70;
constexpr int NH      = 64;
constexpr int EMB     = 128;
constexpr int DD      = 192;
constexpr int RES_HID = 512;
constexpr int PRED_HID= 320;

__device__ __forceinline__ float leaky(float x){ return x > 0.f ? x : 0.01f*x; }

// ===================== CSR build for GCN aggregation ======================
__global__ void k_zero(int* p, int n){
  int i = blockIdx.x*256 + threadIdx.x;
  if (i < n) p[i] = 0;
}
__global__ void k_hist(const int* __restrict__ col, int* __restrict__ cnt, int E){
  int e = blockIdx.x*256 + threadIdx.x;
  if (e < E) atomicAdd(&cnt[col[e]], 1);
}
// phase A: per-block (256-elem) sums
__global__ void k_scanA(const int* __restrict__ cnt, int* __restrict__ bsum, int n){
  __shared__ int s;
  if (threadIdx.x == 0) s = 0;
  __syncthreads();
  int i = blockIdx.x*256 + threadIdx.x;
  int v = (i < n) ? cnt[i] : 0;
  #pragma unroll
  for (int o=32;o;o>>=1) v += __shfl_xor(v, o, 64);
  if ((threadIdx.x & 63) == 0) atomicAdd(&s, v);
  __syncthreads();
  if (threadIdx.x == 0) bsum[blockIdx.x] = s;
}
// phase B: single block, exclusive scan of block sums (robust to nb>256 via carry)
__global__ void k_scanB(int* bsum, int nb){
  __shared__ int s[256];
  __shared__ int carry;
  if (threadIdx.x == 0) carry = 0;
  __syncthreads();
  for (int start = 0; start < nb; start += 256){
    int i = start + threadIdx.x;
    int v = (i < nb) ? bsum[i] : 0;
    s[threadIdx.x] = v; __syncthreads();
    for (int o=1;o<256;o<<=1){
      int t = (threadIdx.x >= o) ? s[threadIdx.x-o] : 0;
      __syncthreads();
      s[threadIdx.x] += t; __syncthreads();
    }
    if (i < nb) bsum[i] = carry + s[threadIdx.x] - v;   // exclusive
    __syncthreads();
    if (threadIdx.x == 255) carry += s[255];
    __syncthreads();
  }
}
// phase C: local exclusive scan + base/cursor/dinv; base[n]=E sentinel
__global__ void k_scanC(const int* __restrict__ cnt, const int* __restrict__ bsum,
                        int* __restrict__ base, int* __restrict__ cursor,
                        float* __restrict__ dinv, int n, int E){
  __shared__ int s[256];
  int i = blockIdx.x*256 + threadIdx.x;
  int v = (i < n) ? cnt[i] : 0;
  s[threadIdx.x] = v; __syncthreads();
  for (int o=1;o<256;o<<=1){
    int t = (threadIdx.x >= o) ? s[threadIdx.x-o] : 0;
    __syncthreads();
    s[threadIdx.x] += t; __syncthreads();
  }
  if (i < n){
    int b = bsum[blockIdx.x] + s[threadIdx.x] - v;
    base[i] = b; cursor[i] = b;
    dinv[i] = rsqrtf((float)(v + 1));   // +1 self loop
  }
  if (i == n-1) base[n] = E;
}
__global__ void k_fill(const int* __restrict__ row, const int* __restrict__ col,
                       const float* __restrict__ dinv, int* __restrict__ cursor,
                       int2* __restrict__ ebin, int E){
  int e = blockIdx.x*256 + threadIdx.x;
  if (e < E){
    int r = row[e], c = col[e];
    int slot = atomicAdd(&cursor[c], 1);
    ebin[slot] = make_int2(r, __float_as_int(dinv[r]));
  }
}

// ===================== discrete embedding =================================
__global__ void k_embed(const int* __restrict__ dx, float* __restrict__ A, int n){
  int idx = blockIdx.x*256 + threadIdx.x;
  if (idx < n*NH){
    int i = idx >> 6, j = idx & 63;
    A[(size_t)i*DD + j] = (float)dx[(size_t)i*NCOLS + j];
  }
}

// ===================== dense layer (J=128), 16 nodes/block ================
// transposed X in LDS (stride 20 floats keeps float4 16B-aligned)
template<int K>
__global__ void k_lin(const float* __restrict__ X, int ldx, int xoff,
                      const float* __restrict__ W, const float* __restrict__ bias,
                      float* __restrict__ out, int ldo, int ooff, int n, int act)
{
  constexpr int ST = 20;
  __shared__ __align__(16) float sxT[K*ST];
  int i0 = blockIdx.x*16;
  for (int idx = threadIdx.x; idx < 16*K; idx += 256){
    int t = idx / K, k = idx - t*K;
    int i = i0 + t;
    sxT[k*ST + t] = (i < n) ? X[(size_t)i*ldx + xoff + k] : 0.f;
  }
  __syncthreads();
  int jj = threadIdx.x & 127;
  int tg = threadIdx.x >> 7;          // t-group 0/1 -> nodes tg*8..tg*8+7
  float b = bias ? bias[jj] : 0.f;
  float acc[8];
  #pragma unroll
  for (int t=0;t<8;t++) acc[t] = b;
  for (int k=0;k<K;k++){
    float w = W[(size_t)k*128 + jj];
    float4 xa = *(const float4*)&sxT[k*ST + tg*8];
    float4 xb = *(const float4*)&sxT[k*ST + tg*8 + 4];
    acc[0] = fmaf(xa.x, w, acc[0]); acc[1] = fmaf(xa.y, w, acc[1]);
    acc[2] = fmaf(xa.z, w, acc[2]); acc[3] = fmaf(xa.w, w, acc[3]);
    acc[4] = fmaf(xb.x, w, acc[4]); acc[5] = fmaf(xb.y, w, acc[5]);
    acc[6] = fmaf(xb.z, w, acc[6]); acc[7] = fmaf(xb.w, w, acc[7]);
  }
  #pragma unroll
  for (int tt=0;tt<8;tt++){
    int i = i0 + tg*8 + tt;
    if (i < n){
      float v = acc[tt];
      if (act) v = leaky(v);
      out[(size_t)i*ldo + ooff + jj] = v;
    }
  }
}

// ===================== GCN aggregation: gather (no atomics) ===============
__global__ void k_gather(const float* __restrict__ h, const float* __restrict__ dinv,
                         const int* __restrict__ base, const int2* __restrict__ ebin,
                         const float* __restrict__ bias, float* __restrict__ out,
                         int ldo, int ooff, int n)
{
  int node = blockIdx.x*4 + (threadIdx.x >> 6);
  int lane = threadIdx.x & 63;
  if (node >= n) return;
  int b0 = base[node], b1 = base[node+1];
  float dc = dinv[node];
  float ax = 0.f, ay = 0.f;
  int e = b0;
  for (; e + 1 < b1; e += 2){
    int2 ea = ebin[e], eb = ebin[e+1];
    float2 ha = ((const float2*)(h + (size_t)ea.x*EMB))[lane];
    float2 hb = ((const float2*)(h + (size_t)eb.x*EMB))[lane];
    float da = __int_as_float(ea.y), db = __int_as_float(eb.y);
    ax = fmaf(ha.x, da, ax); ay = fmaf(ha.y, da, ay);
    ax = fmaf(hb.x, db, ax); ay = fmaf(hb.y, db, ay);
  }
  if (e < b1){
    int2 ea = ebin[e];
    float2 ha = ((const float2*)(h + (size_t)ea.x*EMB))[lane];
    float da = __int_as_float(ea.y);
    ax = fmaf(ha.x, da, ax); ay = fmaf(ha.y, da, ay);
  }
  float2 hc = ((const float2*)(h + (size_t)node*EMB))[lane];
  float vx = leaky((ax + hc.x*dc)*dc + bias[2*lane]);
  float vy = leaky((ay + hc.y*dc)*dc + bias[2*lane+1]);
  float* op = out + (size_t)node*ldo + ooff + 2*lane;
  op[0] = vx; op[1] = vy;
}

// ===================== fused residual bottleneck ==========================
// out = leaky(x + leaky(x@W1+b1)@W2 + b2); 8 nodes/block, transposed LDS
__global__ void k_resblock(const float* __restrict__ X,
                           const float* __restrict__ W1, const float* __restrict__ b1,
                           const float* __restrict__ W2, const float* __restrict__ b2,
                           float* __restrict__ out, int n)
{
  constexpr int ST = 12;
  __shared__ __align__(16) float sxT[DD*ST];
  __shared__ __align__(16) float shT[RES_HID*ST];
  int i0 = blockIdx.x*8;
  for (int idx = threadIdx.x; idx < 8*DD; idx += 256){
    int t = idx / DD, k = idx - t*DD;
    int i = i0 + t;
    sxT[k*ST + t] = (i < n) ? X[(size_t)i*DD + k] : 0.f;
  }
  __syncthreads();
  // GEMM1: [8,192] @ [192,512]; each thread handles j and j+256
  {
    int j1 = threadIdx.x, j2 = threadIdx.x + 256;
    float ba = b1[j1], bb = b1[j2];
    float acc[2][8];
    #pragma unroll
    for (int t=0;t<8;t++){ acc[0][t] = ba; acc[1][t] = bb; }
    for (int k=0;k<DD;k++){
      float4 xa = *(const float4*)&sxT[k*ST];
      float4 xb = *(const float4*)&sxT[k*ST + 4];
      float wa = W1[(size_t)k*RES_HID + j1];
      float wb = W1[(size_t)k*RES_HID + j2];
      acc[0][0]=fmaf(xa.x,wa,acc[0][0]); acc[0][1]=fmaf(xa.y,wa,acc[0][1]);
      acc[0][2]=fmaf(xa.z,wa,acc[0][2]); acc[0][3]=fmaf(xa.w,wa,acc[0][3]);
      acc[0][4]=fmaf(xb.x,wa,acc[0][4]); acc[0][5]=fmaf(xb.y,wa,acc[0][5]);
      acc[0][6]=fmaf(xb.z,wa,acc[0][6]); acc[0][7]=fmaf(xb.w,wa,acc[0][7]);
      acc[1][0]=fmaf(xa.x,wb,acc[1][0]); acc[1][1]=fmaf(xa.y,wb,acc[1][1]);
      acc[1][2]=fmaf(xa.z,wb,acc[1][2]); acc[1][3]=fmaf(xa.w,wb,acc[1][3]);
      acc[1][4]=fmaf(xb.x,wb,acc[1][4]); acc[1][5]=fmaf(xb.y,wb,acc[1][5]);
      acc[1][6]=fmaf(xb.z,wb,acc[1][6]); acc[1][7]=fmaf(xb.w,wb,acc[1][7]);
    }
    *(float4*)&shT[j1*ST]     = make_float4(leaky(acc[0][0]),leaky(acc[0][1]),leaky(acc[0][2]),leaky(acc[0][3]));
    *(float4*)&shT[j1*ST + 4] = make_float4(leaky(acc[0][4]),leaky(acc[0][5]),leaky(acc[0][6]),leaky(acc[0][7]));
    *(float4*)&shT[j2*ST]     = make_float4(leaky(acc[1][0]),leaky(acc[1][1]),leaky(acc[1][2]),leaky(acc[1][3]));
    *(float4*)&shT[j2*ST + 4] = make_float4(leaky(acc[1][4]),leaky(acc[1][5]),leaky(acc[1][6]),leaky(acc[1][7]));
  }
  __syncthreads();
  // GEMM2: [8,512] @ [512,192] + residual
  if (threadIdx.x < DD){
    int j = threadIdx.x;
    float acc[8];
    float b = b2[j];
    #pragma unroll
    for (int t=0;t<8;t++) acc[t] = b;
    for (int k=0;k<RES_HID;k++){
      float4 ha = *(const float4*)&shT[k*ST];
      float4 hb = *(const float4*)&shT[k*ST + 4];
      float w = W2[(size_t)k*DD + j];
      acc[0]=fmaf(ha.x,w,acc[0]); acc[1]=fmaf(ha.y,w,acc[1]);
      acc[2]=fmaf(ha.z,w,acc[2]); acc[3]=fmaf(ha.w,w,acc[3]);
      acc[4]=fmaf(hb.x,w,acc[4]); acc[5]=fmaf(hb.y,w,acc[5]);
      acc[6]=fmaf(hb.z,w,acc[6]); acc[7]=fmaf(hb.w,w,acc[7]);
    }
    #pragma unroll
    for (int t=0;t<8;t++){
      int i = i0 + t;
      if (i < n) out[(size_t)i*DD + j] = leaky(sxT[j*ST + t] + acc[t]);
    }
  }
}

// ===================== CrossNet ==========================================
__global__ void k_cross(const float* __restrict__ X0, const float* __restrict__ cw,
                        const float* __restrict__ cb, float* __restrict__ out, int n)
{
  int node = blockIdx.x*4 + (threadIdx.x >> 6);
  int lane = threadIdx.x & 63;
  if (node >= n) return;
  const float* xr = X0 + (size_t)node*DD;
  float v0[3], xc[3];
  #pragma unroll
  for (int m=0;m<3;m++){ v0[m] = xr[lane + 64*m]; xc[m] = v0[m]; }
  #pragma unroll
  for (int l=0;l<2;l++){
    float p = 0.f;
    #pragma unroll
    for (int m=0;m<3;m++) p += xc[m]*cw[l*DD + lane + 64*m];
    #pragma unroll
    for (int off=32; off>0; off>>=1) p += __shfl_xor(p, off, 64);
    #pragma unroll
    for (int m=0;m<3;m++) xc[m] = v0[m]*p + cb[l*DD + lane + 64*m] + xc[m];
  }
  #pragma unroll
  for (int m=0;m<3;m++) out[(size_t)node*DD + lane + 64*m] = xc[m];
}

// ===================== prediction head (320 threads) ======================
__global__ void k_pred(const float* __restrict__ deep, const float* __restrict__ cross,
                       const float* __restrict__ W1, const float* __restrict__ b1,
                       const float* __restrict__ w2, const float* __restrict__ b2,
                       float* __restrict__ y, int n)
{
  constexpr int ST = 12;
  __shared__ __align__(16) float szT[2*DD*ST];
  __shared__ float sred[5][8];
  int i0 = blockIdx.x*8;
  for (int idx = threadIdx.x; idx < 8*2*DD; idx += 320){
    int t = idx / (2*DD), k = idx - t*(2*DD);
    int i = i0 + t;
    float v = 0.f;
    if (i < n) v = (k < DD) ? deep[(size_t)i*DD + k] : cross[(size_t)i*DD + (k - DD)];
    szT[k*ST + t] = v;
  }
  __syncthreads();
  int j = threadIdx.x;      // 320 threads == PRED_HID
  float acc[8];
  float b = b1[j];
  #pragma unroll
  for (int t=0;t<8;t++) acc[t] = b;
  for (int k=0;k<2*DD;k++){
    float4 xa = *(const float4*)&szT[k*ST];
    float4 xb = *(const float4*)&szT[k*ST + 4];
    float w = W1[(size_t)k*PRED_HID + j];
    acc[0]=fmaf(xa.x,w,acc[0]); acc[1]=fmaf(xa.y,w,acc[1]);
    acc[2]=fmaf(xa.z,w,acc[2]); acc[3]=fmaf(xa.w,w,acc[3]);
    acc[4]=fmaf(xb.x,w,acc[4]); acc[5]=fmaf(xb.y,w,acc[5]);
    acc[6]=fmaf(xb.z,w,acc[6]); acc[7]=fmaf(xb.w,w,acc[7]);
  }
  float w2j = w2[j];
  float part[8];
  #pragma unroll
  for (int t=0;t<8;t++) part[t] = leaky(acc[t])*w2j;
  #pragma unroll
  for (int t=0;t<8;t++){
    #pragma unroll
    for (int off=32; off>0; off>>=1) part[t] += __shfl_xor(part[t], off, 64);
  }
  int wave = threadIdx.x >> 6, lane = threadIdx.x & 63;
  if (lane == 0){
    #pragma unroll
    for (int t=0;t<8;t++) sred[wave][t] = part[t];
  }
  __syncthreads();
  if (threadIdx.x < 8){
    int t = threadIdx.x;
    float s = sred[0][t] + sred[1][t] + sred[2][t] + sred[3][t] + sred[4][t] + b2[0];
    int i = i0 + t;
    if (i < n) y[i] = 1.f/(1.f + expf(-s));
  }
}

extern "C" void kernel_launch(void* const* d_in, const int* in_sizes, int n_in,
                              void* d_out, int out_size, void* d_ws, size_t ws_size,
                              hipStream_t stream)
{
  const int*   dx      = (const int*)d_in[0];
  const int*   ei      = (const int*)d_in[1];
  const float* w_g0    = (const float*)d_in[2];
  const float* b_g0    = (const float*)d_in[3];
  const float* w_gcn1  = (const float*)d_in[4];
  const float* b_gcn1  = (const float*)d_in[5];
  const float* w_gcn2  = (const float*)d_in[6];
  const float* b_gcn2  = (const float*)d_in[7];
  const float* res_w1  = (const float*)d_in[8];
  const float* res_b1  = (const float*)d_in[9];
  const float* res_w2  = (const float*)d_in[10];
  const float* res_b2  = (const float*)d_in[11];
  const float* cross_w = (const float*)d_in[12];
  const float* cross_b = (const float*)d_in[13];
  const float* p_w1    = (const float*)d_in[14];
  const float* p_b1    = (const float*)d_in[15];
  const float* p_w2    = (const float*)d_in[16];
  const float* p_b2    = (const float*)d_in[17];
  float* y = (float*)d_out;

  int n = in_sizes[0] / NCOLS;
  int E = in_sizes[1] / 2;
  const int* row = ei;
  const int* col = ei + E;

  // workspace layout (floats then ints; ~134 MB total)
  float* ws  = (float*)d_ws;
  float* A   = ws;                         // [n,192] x0 (cols 0..63 x_d, 64..191 x_g)
  float* B   = A  + (size_t)192*n;         // [n,192] x_deep
  float* G   = B  + (size_t)192*n;         // [n,256] graph ping/pong; later Dx
  float* E1  = G;                          // [n,128]
  float* E2v = G  + (size_t)128*n;         // [n,128]
  float* Dx  = G;                          // [n,192] x_cross (after graph phase)
  float* dinv= G  + (size_t)256*n;         // [n]
  int*  cnt    = (int*)(dinv + n);         // [n]
  int*  base   = cnt + n;                  // [n+2]
  int*  cursor = base + n + 2;             // [n]
  int*  bsum   = cursor + n;               // [256]
  int2* ebin   = (int2*)((((uintptr_t)(bsum + 256)) + 15) & ~(uintptr_t)15); // [E]

  dim3 blk(256);
  int nb = (n + 255)/256;

  // --- CSR build (also produces dinv) ---
  k_zero <<<nb, blk, 0, stream>>>(cnt, n);
  k_hist <<<(E+255)/256, blk, 0, stream>>>(col, cnt, E);
  k_scanA<<<nb, blk, 0, stream>>>(cnt, bsum, n);
  k_scanB<<<1, blk, 0, stream>>>(bsum, nb);
  k_scanC<<<nb, blk, 0, stream>>>(cnt, bsum, base, cursor, dinv, n, E);
  k_fill <<<(E+255)/256, blk, 0, stream>>>(row, col, dinv, cursor, ebin, E);

  // --- node features ---
  k_embed<<<(n*NH+255)/256, blk, 0, stream>>>(dx, A, n);
  // x_g = leaky(x_d @ w_g0 + b_g0)
  k_lin<64> <<<(n+15)/16, blk, 0, stream>>>(A, DD, 0, w_g0, b_g0, E1, EMB, 0, n, 1);
  // GCN conv 1
  k_lin<128><<<(n+15)/16, blk, 0, stream>>>(E1, EMB, 0, w_gcn1, nullptr, E2v, EMB, 0, n, 0);
  k_gather  <<<(n+3)/4,   blk, 0, stream>>>(E2v, dinv, base, ebin, b_gcn1, E1, EMB, 0, n);
  // GCN conv 2 -> A[:,64:192]
  k_lin<128><<<(n+15)/16, blk, 0, stream>>>(E1, EMB, 0, w_gcn2, nullptr, E2v, EMB, 0, n, 0);
  k_gather  <<<(n+3)/4,   blk, 0, stream>>>(E2v, dinv, base, ebin, b_gcn2, A, DD, NH, n);
  // --- ResDNN ---
  k_resblock<<<(n+7)/8, blk, 0, stream>>>(A, res_w1, res_b1, res_w2, res_b2, B, n);
  k_resblock<<<(n+7)/8, blk, 0, stream>>>(B, res_w1 + (size_t)DD*RES_HID, res_b1 + RES_HID,
                                          res_w2 + (size_t)RES_HID*DD, res_b2 + DD, B, n);
  // --- CrossNet (E1/E2v dead now; Dx aliases G) ---
  k_cross<<<(n+3)/4, blk, 0, stream>>>(A, cross_w, cross_b, Dx, n);
  // --- prediction head ---
  k_pred<<<(n+7)/8, dim3(320), 0, stream>>>(B, Dx, p_w1, p_b1, p_w2, p_b2, y, n);
}

// Round 4
// 917.758 us; speedup vs baseline: 2.1885x; 1.3617x over previous
//
#include <hip/hip_runtime.h>
#include <math.h>

constexpr int NCOLS   = 70;
constexpr int NH      = 64;
constexpr int EMB     = 128;
constexpr int DD      = 192;
constexpr int RES_HID = 512;
constexpr int PRED_HID= 320;

typedef _Float16 f16x8 __attribute__((ext_vector_type(8)));
typedef float    f32x4 __attribute__((ext_vector_type(4)));
#define MFMA16F(a,b,c) __builtin_amdgcn_mfma_f32_16x16x32_f16((a),(b),(c),0,0,0)

constexpr float LO_SCALE   = 4096.0f;     // 2^12: lo words stored pre-scaled
constexpr float LO_DESCALE = 1.0f/4096.0f;
constexpr float Z_SCALE    = 0.0625f;     // 1/16: pred-head z pre-scale (fp16 range)
constexpr float Z_DESCALE  = 16.0f;

__device__ __forceinline__ float leaky(float x){ return x > 0.f ? x : 0.01f*x; }

// ===================== CSR build for GCN aggregation ======================
__global__ void k_zero(int* p, int n){
  int i = blockIdx.x*256 + threadIdx.x;
  if (i < n) p[i] = 0;
}
__global__ void k_hist(const int* __restrict__ col, int* __restrict__ cnt, int E){
  int e = blockIdx.x*256 + threadIdx.x;
  if (e < E) atomicAdd(&cnt[col[e]], 1);
}
__global__ void k_scanA(const int* __restrict__ cnt, int* __restrict__ bsum, int n){
  __shared__ int s;
  if (threadIdx.x == 0) s = 0;
  __syncthreads();
  int i = blockIdx.x*256 + threadIdx.x;
  int v = (i < n) ? cnt[i] : 0;
  #pragma unroll
  for (int o=32;o;o>>=1) v += __shfl_xor(v, o, 64);
  if ((threadIdx.x & 63) == 0) atomicAdd(&s, v);
  __syncthreads();
  if (threadIdx.x == 0) bsum[blockIdx.x] = s;
}
__global__ void k_scanB(int* bsum, int nb){
  __shared__ int s[256];
  __shared__ int carry;
  if (threadIdx.x == 0) carry = 0;
  __syncthreads();
  for (int start = 0; start < nb; start += 256){
    int i = start + threadIdx.x;
    int v = (i < nb) ? bsum[i] : 0;
    s[threadIdx.x] = v; __syncthreads();
    for (int o=1;o<256;o<<=1){
      int t = (threadIdx.x >= o) ? s[threadIdx.x-o] : 0;
      __syncthreads();
      s[threadIdx.x] += t; __syncthreads();
    }
    if (i < nb) bsum[i] = carry + s[threadIdx.x] - v;
    __syncthreads();
    if (threadIdx.x == 255) carry += s[255];
    __syncthreads();
  }
}
__global__ void k_scanC(const int* __restrict__ cnt, const int* __restrict__ bsum,
                        int* __restrict__ base, int* __restrict__ cursor,
                        float* __restrict__ dinv, int n, int E){
  __shared__ int s[256];
  int i = blockIdx.x*256 + threadIdx.x;
  int v = (i < n) ? cnt[i] : 0;
  s[threadIdx.x] = v; __syncthreads();
  for (int o=1;o<256;o<<=1){
    int t = (threadIdx.x >= o) ? s[threadIdx.x-o] : 0;
    __syncthreads();
    s[threadIdx.x] += t; __syncthreads();
  }
  if (i < n){
    int b = bsum[blockIdx.x] + s[threadIdx.x] - v;
    base[i] = b; cursor[i] = b;
    dinv[i] = rsqrtf((float)(v + 1));
  }
  if (i == n-1) base[n] = E;
}
__global__ void k_fill(const int* __restrict__ row, const int* __restrict__ col,
                       const float* __restrict__ dinv, int* __restrict__ cursor,
                       int2* __restrict__ ebin, int E){
  int e = blockIdx.x*256 + threadIdx.x;
  if (e < E){
    int r = row[e], c = col[e];
    int slot = atomicAdd(&cursor[c], 1);
    ebin[slot] = make_int2(r, __float_as_int(dinv[r]));
  }
}

// ===== weight prep: fp32 [K][N] -> fp16 hi/lo(x4096) transposed [N][K] ====
__global__ void k_wprep(const float* __restrict__ W, _Float16* __restrict__ Wh,
                        _Float16* __restrict__ Wl, int K, int N){
  int idx = blockIdx.x*256 + threadIdx.x;
  if (idx < K*N){
    int k = idx / N, nn = idx - k*N;
    float v = W[idx];
    _Float16 h = (_Float16)v;
    float lo = (v - (float)h)*LO_SCALE;
    Wh[(size_t)nn*K + k] = h;
    Wl[(size_t)nn*K + k] = (_Float16)lo;
  }
}

// ===================== discrete embedding =================================
__global__ void k_embed(const int* __restrict__ dx, float* __restrict__ A, int n){
  int idx = blockIdx.x*256 + threadIdx.x;
  if (idx < n*NH){
    int i = idx >> 6, j = idx & 63;
    A[(size_t)i*DD + j] = (float)dx[(size_t)i*NCOLS + j];
  }
}

// ===================== dense layer (J=128), 16 nodes/block ================
template<int K>
__global__ void k_lin(const float* __restrict__ X, int ldx, int xoff,
                      const float* __restrict__ W, const float* __restrict__ bias,
                      float* __restrict__ out, int ldo, int ooff, int n, int act)
{
  constexpr int ST = 20;
  __shared__ __align__(16) float sxT[K*ST];
  int i0 = blockIdx.x*16;
  for (int idx = threadIdx.x; idx < 16*K; idx += 256){
    int t = idx / K, k = idx - t*K;
    int i = i0 + t;
    sxT[k*ST + t] = (i < n) ? X[(size_t)i*ldx + xoff + k] : 0.f;
  }
  __syncthreads();
  int jj = threadIdx.x & 127;
  int tg = threadIdx.x >> 7;
  float b = bias ? bias[jj] : 0.f;
  float acc[8];
  #pragma unroll
  for (int t=0;t<8;t++) acc[t] = b;
  for (int k=0;k<K;k++){
    float w = W[(size_t)k*128 + jj];
    float4 xa = *(const float4*)&sxT[k*ST + tg*8];
    float4 xb = *(const float4*)&sxT[k*ST + tg*8 + 4];
    acc[0] = fmaf(xa.x, w, acc[0]); acc[1] = fmaf(xa.y, w, acc[1]);
    acc[2] = fmaf(xa.z, w, acc[2]); acc[3] = fmaf(xa.w, w, acc[3]);
    acc[4] = fmaf(xb.x, w, acc[4]); acc[5] = fmaf(xb.y, w, acc[5]);
    acc[6] = fmaf(xb.z, w, acc[6]); acc[7] = fmaf(xb.w, w, acc[7]);
  }
  #pragma unroll
  for (int tt=0;tt<8;tt++){
    int i = i0 + tg*8 + tt;
    if (i < n){
      float v = acc[tt];
      if (act) v = leaky(v);
      out[(size_t)i*ldo + ooff + jj] = v;
    }
  }
}

// ===================== GCN aggregation: gather (no atomics) ===============
__global__ void k_gather(const float* __restrict__ h, const float* __restrict__ dinv,
                         const int* __restrict__ base, const int2* __restrict__ ebin,
                         const float* __restrict__ bias, float* __restrict__ out,
                         int ldo, int ooff, int n)
{
  int node = blockIdx.x*4 + (threadIdx.x >> 6);
  int lane = threadIdx.x & 63;
  if (node >= n) return;
  int b0 = base[node], b1 = base[node+1];
  float dc = dinv[node];
  float ax = 0.f, ay = 0.f;
  int e = b0;
  for (; e + 1 < b1; e += 2){
    int2 ea = ebin[e], eb = ebin[e+1];
    float2 ha = ((const float2*)(h + (size_t)ea.x*EMB))[lane];
    float2 hb = ((const float2*)(h + (size_t)eb.x*EMB))[lane];
    float da = __int_as_float(ea.y), db = __int_as_float(eb.y);
    ax = fmaf(ha.x, da, ax); ay = fmaf(ha.y, da, ay);
    ax = fmaf(hb.x, db, ax); ay = fmaf(hb.y, db, ay);
  }
  if (e < b1){
    int2 ea = ebin[e];
    float2 ha = ((const float2*)(h + (size_t)ea.x*EMB))[lane];
    float da = __int_as_float(ea.y);
    ax = fmaf(ha.x, da, ax); ay = fmaf(ha.y, da, ay);
  }
  float2 hc = ((const float2*)(h + (size_t)node*EMB))[lane];
  float vx = leaky((ax + hc.x*dc)*dc + bias[2*lane]);
  float vy = leaky((ay + hc.y*dc)*dc + bias[2*lane+1]);
  float* op = out + (size_t)node*ldo + ooff + 2*lane;
  op[0] = vx; op[1] = vy;
}

// ===================== MFMA residual bottleneck (fp16 hi/lo) ==============
// 32 rows/block, 4 waves over output cols. GEMM1: xh*wh + (xl_s*wh + xh*wl_s)/4096.
// GEMM2: H single fp16; acc + (H*wl_s)/4096.
constexpr int XS = 200;   // X LDS row stride (halves): 400B = 100 dw ≡ 4 (mod 32)
constexpr int HS = 520;   // H LDS row stride (halves): 1040B = 260 dw ≡ 4 (mod 32)

__global__ __launch_bounds__(256,2)
void k_resblock_mfma(const float* __restrict__ X,
                     const _Float16* __restrict__ W1h, const _Float16* __restrict__ W1l,
                     const float* __restrict__ b1,
                     const _Float16* __restrict__ W2h, const _Float16* __restrict__ W2l,
                     const float* __restrict__ b2,
                     float* __restrict__ out, int n)
{
  __shared__ __align__(16) _Float16 xh[32*XS];
  __shared__ __align__(16) _Float16 xl[32*XS];
  __shared__ __align__(16) _Float16 hh[32*HS];
  int i0 = blockIdx.x*32;
  for (int idx = threadIdx.x; idx < 32*DD; idx += 256){
    int t = idx / DD, k = idx - t*DD;
    int i = i0 + t;
    float v = (i < n) ? X[(size_t)i*DD + k] : 0.f;
    _Float16 h = (_Float16)v;
    float lo = (v - (float)h)*LO_SCALE;
    xh[t*XS + k] = h;
    xl[t*XS + k] = (_Float16)lo;
  }
  __syncthreads();
  int wv = threadIdx.x >> 6, ln = threadIdx.x & 63;
  int cn = ln & 15, kg = ln >> 4;
  // ---- GEMM1: H[32x512] = X @ W1
  #pragma unroll 1
  for (int ct = 0; ct < 8; ct++){
    int n0 = wv*128 + ct*16;
    f32x4 acc0 = {0.f,0.f,0.f,0.f}, accL0 = {0.f,0.f,0.f,0.f};
    f32x4 acc1 = {0.f,0.f,0.f,0.f}, accL1 = {0.f,0.f,0.f,0.f};
    const _Float16* wrh = W1h + (size_t)(n0 + cn)*DD + kg*8;
    const _Float16* wrl = W1l + (size_t)(n0 + cn)*DD + kg*8;
    #pragma unroll
    for (int k0 = 0; k0 < DD; k0 += 32){
      f16x8 bh = *(const f16x8*)(wrh + k0);
      f16x8 bl = *(const f16x8*)(wrl + k0);
      f16x8 a0h = *(const f16x8*)&xh[cn*XS + k0 + kg*8];
      f16x8 a0l = *(const f16x8*)&xl[cn*XS + k0 + kg*8];
      f16x8 a1h = *(const f16x8*)&xh[(16+cn)*XS + k0 + kg*8];
      f16x8 a1l = *(const f16x8*)&xl[(16+cn)*XS + k0 + kg*8];
      acc0  = MFMA16F(a0h, bh, acc0);
      accL0 = MFMA16F(a0l, bh, accL0);
      accL0 = MFMA16F(a0h, bl, accL0);
      acc1  = MFMA16F(a1h, bh, acc1);
      accL1 = MFMA16F(a1l, bh, accL1);
      accL1 = MFMA16F(a1h, bl, accL1);
    }
    float bb = b1[n0 + cn];
    #pragma unroll
    for (int r=0;r<4;r++){
      hh[(kg*4+r)*HS + n0 + cn]    = (_Float16)leaky(acc0[r] + accL0[r]*LO_DESCALE + bb);
      hh[(16+kg*4+r)*HS + n0 + cn] = (_Float16)leaky(acc1[r] + accL1[r]*LO_DESCALE + bb);
    }
  }
  __syncthreads();
  // ---- GEMM2: C[32x192] = H @ W2 + residual
  #pragma unroll 1
  for (int ct = 0; ct < 3; ct++){
    int n0 = (wv*3 + ct)*16;
    f32x4 acc0 = {0.f,0.f,0.f,0.f}, accL0 = {0.f,0.f,0.f,0.f};
    f32x4 acc1 = {0.f,0.f,0.f,0.f}, accL1 = {0.f,0.f,0.f,0.f};
    const _Float16* wrh = W2h + (size_t)(n0 + cn)*RES_HID + kg*8;
    const _Float16* wrl = W2l + (size_t)(n0 + cn)*RES_HID + kg*8;
    #pragma unroll 4
    for (int k0 = 0; k0 < RES_HID; k0 += 32){
      f16x8 bh = *(const f16x8*)(wrh + k0);
      f16x8 bl = *(const f16x8*)(wrl + k0);
      f16x8 a0 = *(const f16x8*)&hh[cn*HS + k0 + kg*8];
      f16x8 a1 = *(const f16x8*)&hh[(16+cn)*HS + k0 + kg*8];
      acc0  = MFMA16F(a0, bh, acc0);
      accL0 = MFMA16F(a0, bl, accL0);
      acc1  = MFMA16F(a1, bh, acc1);
      accL1 = MFMA16F(a1, bl, accL1);
    }
    float bb = b2[n0 + cn];
    #pragma unroll
    for (int r=0;r<4;r++){
      int m0 = kg*4 + r, m1 = 16 + kg*4 + r;
      float res0 = (float)xh[m0*XS + n0 + cn] + (float)xl[m0*XS + n0 + cn]*LO_DESCALE;
      float res1 = (float)xh[m1*XS + n0 + cn] + (float)xl[m1*XS + n0 + cn]*LO_DESCALE;
      int ia = i0 + m0, ib = i0 + m1;
      if (ia < n) out[(size_t)ia*DD + n0 + cn] = leaky(res0 + acc0[r] + accL0[r]*LO_DESCALE + bb);
      if (ib < n) out[(size_t)ib*DD + n0 + cn] = leaky(res1 + acc1[r] + accL1[r]*LO_DESCALE + bb);
    }
  }
}

// ===================== CrossNet ==========================================
__global__ void k_cross(const float* __restrict__ X0, const float* __restrict__ cw,
                        const float* __restrict__ cb, float* __restrict__ out, int n)
{
  int node = blockIdx.x*4 + (threadIdx.x >> 6);
  int lane = threadIdx.x & 63;
  if (node >= n) return;
  const float* xr = X0 + (size_t)node*DD;
  float v0[3], xc[3];
  #pragma unroll
  for (int m=0;m<3;m++){ v0[m] = xr[lane + 64*m]; xc[m] = v0[m]; }
  #pragma unroll
  for (int l=0;l<2;l++){
    float p = 0.f;
    #pragma unroll
    for (int m=0;m<3;m++) p += xc[m]*cw[l*DD + lane + 64*m];
    #pragma unroll
    for (int off=32; off>0; off>>=1) p += __shfl_xor(p, off, 64);
    #pragma unroll
    for (int m=0;m<3;m++) xc[m] = v0[m]*p + cb[l*DD + lane + 64*m] + xc[m];
  }
  #pragma unroll
  for (int m=0;m<3;m++) out[(size_t)node*DD + lane + 64*m] = xc[m];
}

// ===================== MFMA prediction head (fp16 hi/lo, z/16) ============
constexpr int ZS = 392;   // z LDS row stride (halves): 784B = 196 dw ≡ 4 (mod 32)

__global__ __launch_bounds__(256,2)
void k_pred_mfma(const float* __restrict__ deep, const float* __restrict__ cross,
                 const _Float16* __restrict__ Wh, const _Float16* __restrict__ Wl,
                 const float* __restrict__ b1,
                 const float* __restrict__ w2, const float* __restrict__ b2,
                 float* __restrict__ y, int n)
{
  __shared__ __align__(16) _Float16 zh[32*ZS];
  __shared__ __align__(16) _Float16 zl[32*ZS];
  __shared__ float sred[4][32];
  int i0 = blockIdx.x*32;
  for (int idx = threadIdx.x; idx < 32*2*DD; idx += 256){
    int t = idx / (2*DD), k = idx - t*(2*DD);
    int i = i0 + t;
    float v = 0.f;
    if (i < n) v = (k < DD) ? deep[(size_t)i*DD + k] : cross[(size_t)i*DD + (k - DD)];
    v *= Z_SCALE;
    _Float16 h = (_Float16)v;
    float lo = (v - (float)h)*LO_SCALE;
    zh[t*ZS + k] = h;
    zl[t*ZS + k] = (_Float16)lo;
  }
  __syncthreads();
  int wv = threadIdx.x >> 6, ln = threadIdx.x & 63;
  int cn = ln & 15, kg = ln >> 4;
  float vs0[4] = {0.f,0.f,0.f,0.f};
  float vs1[4] = {0.f,0.f,0.f,0.f};
  #pragma unroll 1
  for (int ct = 0; ct < 5; ct++){
    int n0 = wv*80 + ct*16;
    f32x4 acc0 = {0.f,0.f,0.f,0.f}, accL0 = {0.f,0.f,0.f,0.f};
    f32x4 acc1 = {0.f,0.f,0.f,0.f}, accL1 = {0.f,0.f,0.f,0.f};
    const _Float16* wrh = Wh + (size_t)(n0 + cn)*(2*DD) + kg*8;
    const _Float16* wrl = Wl + (size_t)(n0 + cn)*(2*DD) + kg*8;
    #pragma unroll 4
    for (int k0 = 0; k0 < 2*DD; k0 += 32){
      f16x8 bh = *(const f16x8*)(wrh + k0);
      f16x8 bl = *(const f16x8*)(wrl + k0);
      f16x8 a0h = *(const f16x8*)&zh[cn*ZS + k0 + kg*8];
      f16x8 a0l = *(const f16x8*)&zl[cn*ZS + k0 + kg*8];
      f16x8 a1h = *(const f16x8*)&zh[(16+cn)*ZS + k0 + kg*8];
      f16x8 a1l = *(const f16x8*)&zl[(16+cn)*ZS + k0 + kg*8];
      acc0  = MFMA16F(a0h, bh, acc0);
      accL0 = MFMA16F(a0l, bh, accL0);
      accL0 = MFMA16F(a0h, bl, accL0);
      acc1  = MFMA16F(a1h, bh, acc1);
      accL1 = MFMA16F(a1l, bh, accL1);
      accL1 = MFMA16F(a1h, bl, accL1);
    }
    float bb = b1[n0 + cn];
    float ww = w2[n0 + cn];
    #pragma unroll
    for (int r=0;r<4;r++){
      float v0 = (acc0[r] + accL0[r]*LO_DESCALE)*Z_DESCALE + bb;
      float v1 = (acc1[r] + accL1[r]*LO_DESCALE)*Z_DESCALE + bb;
      vs0[r] += leaky(v0)*ww;
      vs1[r] += leaky(v1)*ww;
    }
  }
  #pragma unroll
  for (int r=0;r<4;r++){
    #pragma unroll
    for (int off=1; off<16; off<<=1){
      vs0[r] += __shfl_xor(vs0[r], off, 64);
      vs1[r] += __shfl_xor(vs1[r], off, 64);
    }
  }
  if (cn == 0){
    #pragma unroll
    for (int r=0;r<4;r++){
      sred[wv][kg*4 + r]      = vs0[r];
      sred[wv][16 + kg*4 + r] = vs1[r];
    }
  }
  __syncthreads();
  if (threadIdx.x < 32){
    int m = threadIdx.x;
    float s = sred[0][m] + sred[1][m] + sred[2][m] + sred[3][m] + b2[0];
    int i = i0 + m;
    if (i < n) y[i] = 1.f/(1.f + expf(-s));
  }
}

extern "C" void kernel_launch(void* const* d_in, const int* in_sizes, int n_in,
                              void* d_out, int out_size, void* d_ws, size_t ws_size,
                              hipStream_t stream)
{
  const int*   dx      = (const int*)d_in[0];
  const int*   ei      = (const int*)d_in[1];
  const float* w_g0    = (const float*)d_in[2];
  const float* b_g0    = (const float*)d_in[3];
  const float* w_gcn1  = (const float*)d_in[4];
  const float* b_gcn1  = (const float*)d_in[5];
  const float* w_gcn2  = (const float*)d_in[6];
  const float* b_gcn2  = (const float*)d_in[7];
  const float* res_w1  = (const float*)d_in[8];
  const float* res_b1  = (const float*)d_in[9];
  const float* res_w2  = (const float*)d_in[10];
  const float* res_b2  = (const float*)d_in[11];
  const float* cross_w = (const float*)d_in[12];
  const float* cross_b = (const float*)d_in[13];
  const float* p_w1    = (const float*)d_in[14];
  const float* p_b1    = (const float*)d_in[15];
  const float* p_w2    = (const float*)d_in[16];
  const float* p_b2    = (const float*)d_in[17];
  float* y = (float*)d_out;

  int n = in_sizes[0] / NCOLS;
  int E = in_sizes[1] / 2;
  const int* row = ei;
  const int* col = ei + E;

  float* ws  = (float*)d_ws;
  float* A   = ws;                         // [n,192] x0
  float* B   = A  + (size_t)192*n;         // [n,192] x_deep
  float* G   = B  + (size_t)192*n;         // [n,256] graph ping/pong; later Dx
  float* E1  = G;                          // [n,128]
  float* E2v = G  + (size_t)128*n;         // [n,128]
  float* Dx  = G;                          // [n,192] x_cross (after graph phase)
  float* dinv= G  + (size_t)256*n;         // [n]
  int*  cnt    = (int*)(dinv + n);         // [n]
  int*  base   = cnt + n;                  // [n+2]
  int*  cursor = base + n + 2;             // [n]
  int*  bsum   = cursor + n;               // [256]
  int2* ebin   = (int2*)((((uintptr_t)(bsum + 256)) + 15) & ~(uintptr_t)15); // [E]
  _Float16* wt1h = (_Float16*)((((uintptr_t)(ebin + E)) + 15) & ~(uintptr_t)15);
  _Float16* wt1l = wt1h + (size_t)2*RES_HID*DD;
  _Float16* wt2h = wt1l + (size_t)2*RES_HID*DD;
  _Float16* wt2l = wt2h + (size_t)2*RES_HID*DD;
  _Float16* wph  = wt2l + (size_t)2*RES_HID*DD;
  _Float16* wpl  = wph  + (size_t)PRED_HID*2*DD;

  dim3 blk(256);
  int nb = (n + 255)/256;

  // --- weight prep ---
  {
    int sz = DD*RES_HID;
    k_wprep<<<(sz+255)/256, blk, 0, stream>>>(res_w1,       wt1h,       wt1l,       DD, RES_HID);
    k_wprep<<<(sz+255)/256, blk, 0, stream>>>(res_w1 + sz,  wt1h + sz,  wt1l + sz,  DD, RES_HID);
    k_wprep<<<(sz+255)/256, blk, 0, stream>>>(res_w2,       wt2h,       wt2l,       RES_HID, DD);
    k_wprep<<<(sz+255)/256, blk, 0, stream>>>(res_w2 + sz,  wt2h + sz,  wt2l + sz,  RES_HID, DD);
    int pz = 2*DD*PRED_HID;
    k_wprep<<<(pz+255)/256, blk, 0, stream>>>(p_w1, wph, wpl, 2*DD, PRED_HID);
  }

  // --- CSR build (also produces dinv) ---
  k_zero <<<nb, blk, 0, stream>>>(cnt, n);
  k_hist <<<(E+255)/256, blk, 0, stream>>>(col, cnt, E);
  k_scanA<<<nb, blk, 0, stream>>>(cnt, bsum, n);
  k_scanB<<<1, blk, 0, stream>>>(bsum, nb);
  k_scanC<<<nb, blk, 0, stream>>>(cnt, bsum, base, cursor, dinv, n, E);
  k_fill <<<(E+255)/256, blk, 0, stream>>>(row, col, dinv, cursor, ebin, E);

  // --- node features ---
  k_embed<<<(n*NH+255)/256, blk, 0, stream>>>(dx, A, n);
  k_lin<64> <<<(n+15)/16, blk, 0, stream>>>(A, DD, 0, w_g0, b_g0, E1, EMB, 0, n, 1);
  k_lin<128><<<(n+15)/16, blk, 0, stream>>>(E1, EMB, 0, w_gcn1, nullptr, E2v, EMB, 0, n, 0);
  k_gather  <<<(n+3)/4,   blk, 0, stream>>>(E2v, dinv, base, ebin, b_gcn1, E1, EMB, 0, n);
  k_lin<128><<<(n+15)/16, blk, 0, stream>>>(E1, EMB, 0, w_gcn2, nullptr, E2v, EMB, 0, n, 0);
  k_gather  <<<(n+3)/4,   blk, 0, stream>>>(E2v, dinv, base, ebin, b_gcn2, A, DD, NH, n);
  // --- ResDNN (MFMA) ---
  int rbt = (n + 31)/32;
  k_resblock_mfma<<<rbt, blk, 0, stream>>>(A, wt1h, wt1l, res_b1,
                                           wt2h, wt2l, res_b2, B, n);
  k_resblock_mfma<<<rbt, blk, 0, stream>>>(B, wt1h + (size_t)DD*RES_HID, wt1l + (size_t)DD*RES_HID,
                                           res_b1 + RES_HID,
                                           wt2h + (size_t)DD*RES_HID, wt2l + (size_t)DD*RES_HID,
                                           res_b2 + DD, B, n);
  // --- CrossNet ---
  k_cross<<<(n+3)/4, blk, 0, stream>>>(A, cross_w, cross_b, Dx, n);
  // --- prediction head (MFMA) ---
  k_pred_mfma<<<rbt, blk, 0, stream>>>(B, Dx, wph, wpl, p_b1, p_w2, p_b2, y, n);
}